// Round 2
// baseline (248.295 us; speedup 1.0000x reference)
//
#include <hip/hip_runtime.h>
#include <hip/hip_bf16.h>

#define B_ 16
#define L_ 1024
#define DM 256
#define DI 512
#define NS 16
#define E48 48
#define GCH 16
#define LC 64

// ws layout (float offsets)
#define O_XPRE 0ULL                 // (B,L,DI) pre-conv x (dead after conv; reused by LG/TSUM)
#define O_LG   O_XPRE               // (B,G,DI,16) chunk partial states (2,097,152 f)
#define O_TSUM (2097152ULL)         // (B,G,DI) chunk dt sums (131,072 f)
#define O_XS   (8388608ULL)         // (B,L,DI) conv+silu x
#define O_XDBL (16777216ULL)        // (B,L,48)
#define O_WINT (17563648ULL)        // w_in top-half transposed (256x512)
#define O_WXT  (17694720ULL)        // w_x transposed+padded (512x64)
#define O_ZS   (17727488ULL)        // (B,DI) silu(z_last)
#define O_YF   (17735680ULL)        // (B,DI) final y
// total = 17743872 floats = 71.0 MB

__device__ __forceinline__ float siluf(float v) { return v / (1.f + __expf(-v)); }
__device__ __forceinline__ float softplusf(float v) { return (v > 20.f) ? v : log1pf(__expf(v)); }

// ---- prep: LDS-tiled transpose of w_in top half (512x256 -> 256x512) and
// ---- w_x (48x512 -> 512x64 zero-padded) ----
__global__ __launch_bounds__(256) void k_prep(const float* __restrict__ w_in,
                                              const float* __restrict__ w_x,
                                              float* __restrict__ ws) {
    int bk = blockIdx.x, t = threadIdx.x;
    if (bk < 128) {
        // w_in tile transpose: src (e,k) 512x256, dst winT (k,e) 256x512
        __shared__ float s[32][33];
        int e0 = (bk & 15) * 32, k0 = (bk >> 4) * 32;
        int tx = t & 31, ty = t >> 5;  // ty 0..7
#pragma unroll
        for (int j = 0; j < 4; j++)
            s[ty + 8 * j][tx] = w_in[(size_t)(e0 + ty + 8 * j) * DM + k0 + tx];
        __syncthreads();
        float* winT = ws + O_WINT;
#pragma unroll
        for (int j = 0; j < 4; j++)
            winT[(size_t)(k0 + ty + 8 * j) * DI + e0 + tx] = s[tx][ty + 8 * j];
    } else {
        int e = bk - 128;  // 0..63
        float* wxT = ws + O_WXT;
        for (int k = t; k < DI; k += 256)
            wxT[(size_t)k * 64 + e] = (e < 48) ? w_x[(size_t)e * DI + k] : 0.f;
    }
}

// ---- z at last position only: zs[b,d] = silu(u[b,lb] . w_in[512+d,:]) ----
__global__ void k_zlast(const int* __restrict__ rna, const int* __restrict__ tid_,
                        const int* __restrict__ slen, const float* __restrict__ tis_emb,
                        const float* __restrict__ seq_emb, const float* __restrict__ w_in,
                        float* __restrict__ ws) {
    int b = blockIdx.x, t = threadIdx.x;
    __shared__ float su[DM];
    int lb = slen[b] - 1;
    if (t < 192) { int tok = rna[b * L_ + lb]; su[t] = seq_emb[(size_t)tok * 192 + t]; }
    else         { su[t] = tis_emb[(size_t)tid_[b] * 64 + (t - 192)]; }
    __syncthreads();
    for (int d = t; d < DI; d += 256) {
        const float* wr = w_in + (size_t)(DI + d) * DM;
        float acc = 0.f;
        for (int k = 0; k < DM; k++) acc += su[k] * wr[k];
        ws[O_ZS + (size_t)b * DI + d] = siluf(acc);
    }
}

// ---- GEMM1 (fused embedding): x_pre[b,l,e] = u[b,l,:] . w_in[e,:], e<512 ----
__global__ __launch_bounds__(256) void k_gemm1(const int* __restrict__ rna,
        const int* __restrict__ tid_, const int* __restrict__ slen,
        const float* __restrict__ tis_emb, const float* __restrict__ seq_emb,
        float* __restrict__ ws) {
    int n0 = blockIdx.x * 64;
    int rb = blockIdx.y;
    int b = rb >> 4, l0 = (rb & 15) * 64;
    int lb = slen[b] - 1;
    if (l0 > lb) return;
    const float* winT = ws + O_WINT;
    __shared__ float As[16][64];
    __shared__ float Bs[16][64];
    __shared__ int   stok[64];
    __shared__ float stis[64];
    int t = threadIdx.x;
    if (t < 64) stok[t] = rna[b * L_ + l0 + t];
    else if (t < 128) stis[t - 64] = tis_emb[(size_t)tid_[b] * 64 + (t - 64)];
    __syncthreads();
    float acc[4][4] = {};
    int tx = t & 15, ty = t >> 4;
    int lr = t & 63, kg = t >> 6;         // A-load mapping
    int lc4 = (t & 15) * 4, lkk = t >> 4; // B-load mapping
    for (int k0 = 0; k0 < DM; k0 += 16) {
        int kbase = k0 + kg * 4;
        if (kbase < 192) {
            float4 v = *(const float4*)(seq_emb + (size_t)stok[lr] * 192 + kbase);
            As[kg * 4 + 0][lr] = v.x; As[kg * 4 + 1][lr] = v.y;
            As[kg * 4 + 2][lr] = v.z; As[kg * 4 + 3][lr] = v.w;
        } else {
            As[kg * 4 + 0][lr] = stis[kbase - 192 + 0];
            As[kg * 4 + 1][lr] = stis[kbase - 192 + 1];
            As[kg * 4 + 2][lr] = stis[kbase - 192 + 2];
            As[kg * 4 + 3][lr] = stis[kbase - 192 + 3];
        }
        float4 w = *(const float4*)(winT + (size_t)(k0 + lkk) * DI + n0 + lc4);
        Bs[lkk][lc4 + 0] = w.x; Bs[lkk][lc4 + 1] = w.y;
        Bs[lkk][lc4 + 2] = w.z; Bs[lkk][lc4 + 3] = w.w;
        __syncthreads();
#pragma unroll
        for (int kk = 0; kk < 16; kk++) {
            float4 a = *(const float4*)&As[kk][ty * 4];
            float4 bb = *(const float4*)&Bs[kk][tx * 4];
            acc[0][0] += a.x * bb.x; acc[0][1] += a.x * bb.y; acc[0][2] += a.x * bb.z; acc[0][3] += a.x * bb.w;
            acc[1][0] += a.y * bb.x; acc[1][1] += a.y * bb.y; acc[1][2] += a.y * bb.z; acc[1][3] += a.y * bb.w;
            acc[2][0] += a.z * bb.x; acc[2][1] += a.z * bb.y; acc[2][2] += a.z * bb.z; acc[2][3] += a.z * bb.w;
            acc[3][0] += a.w * bb.x; acc[3][1] += a.w * bb.y; acc[3][2] += a.w * bb.z; acc[3][3] += a.w * bb.w;
        }
        __syncthreads();
    }
#pragma unroll
    for (int i = 0; i < 4; i++) {
        float4 v = make_float4(acc[i][0], acc[i][1], acc[i][2], acc[i][3]);
        *(float4*)(ws + O_XPRE + (size_t)(b * L_ + l0 + ty * 4 + i) * DI + n0 + tx * 4) = v;
    }
}

// ---- causal depthwise conv (k=4) + bias + silu ----
__global__ void k_conv(const int* __restrict__ slen, const float* __restrict__ conv_w,
                       const float* __restrict__ conv_b, float* __restrict__ ws) {
    int b = blockIdx.y, l0 = blockIdx.x * 64;
    int lb = slen[b] - 1;
    if (l0 > lb) return;
    int lmax = min(l0 + 63, lb);
    const float* xp = ws + O_XPRE;
    float* xs = ws + O_XS;
    for (int dd = 0; dd < 2; dd++) {
        int d = threadIdx.x + dd * 256;
        float w0 = conv_w[d * 4 + 0], w1 = conv_w[d * 4 + 1];
        float w2 = conv_w[d * 4 + 2], w3 = conv_w[d * 4 + 3];
        float bias = conv_b[d];
        size_t base = (size_t)b * L_ * DI + d;
        float xm3 = (l0 - 3 >= 0) ? xp[base + (size_t)(l0 - 3) * DI] : 0.f;
        float xm2 = (l0 - 2 >= 0) ? xp[base + (size_t)(l0 - 2) * DI] : 0.f;
        float xm1 = (l0 - 1 >= 0) ? xp[base + (size_t)(l0 - 1) * DI] : 0.f;
        for (int l = l0; l <= lmax; l++) {
            float cur = xp[base + (size_t)l * DI];
            float v = fmaf(w0, xm3, fmaf(w1, xm2, fmaf(w2, xm1, fmaf(w3, cur, bias))));
            xs[base + (size_t)l * DI] = siluf(v);
            xm3 = xm2; xm2 = xm1; xm1 = cur;
        }
    }
}

// ---- x_dbl: tiled GEMM, M=16384 N=48(pad 64) K=512 ----
#define XKC 64
__global__ __launch_bounds__(256) void k_xdbl(const int* __restrict__ slen,
                                              float* __restrict__ ws) {
    int rb = blockIdx.x;
    int b = rb >> 4, l0 = (rb & 15) * 64;
    int lb = slen[b] - 1;
    if (l0 > lb) return;
    const float* xs = ws + O_XS;
    const float* wxT = ws + O_WXT;
    float* xd = ws + O_XDBL;
    __shared__ float As[XKC][64];
    __shared__ float Bs[XKC][64];
    int t = threadIdx.x;
    int tx = t & 15, ty = t >> 4;
    float acc[4][4] = {};
    for (int k0 = 0; k0 < DI; k0 += XKC) {
#pragma unroll
        for (int j = 0; j < 4; j++) {
            int idx = t + 256 * j;
            int r = idx & 63, kq = idx >> 6;  // kq 0..15
            float4 v = *(const float4*)(xs + (size_t)(b * L_ + l0 + r) * DI + k0 + kq * 4);
            As[kq * 4 + 0][r] = v.x; As[kq * 4 + 1][r] = v.y;
            As[kq * 4 + 2][r] = v.z; As[kq * 4 + 3][r] = v.w;
        }
#pragma unroll
        for (int j = 0; j < 4; j++) {
            int idx = t + 256 * j;
            int kk = idx >> 4, e4 = (idx & 15) * 4;
            *(float4*)&Bs[kk][e4] = *(const float4*)(wxT + (size_t)(k0 + kk) * 64 + e4);
        }
        __syncthreads();
#pragma unroll 16
        for (int kk = 0; kk < XKC; kk++) {
            float4 a = *(const float4*)&As[kk][ty * 4];
            float4 bb = *(const float4*)&Bs[kk][tx * 4];
            acc[0][0] += a.x * bb.x; acc[0][1] += a.x * bb.y; acc[0][2] += a.x * bb.z; acc[0][3] += a.x * bb.w;
            acc[1][0] += a.y * bb.x; acc[1][1] += a.y * bb.y; acc[1][2] += a.y * bb.z; acc[1][3] += a.y * bb.w;
            acc[2][0] += a.z * bb.x; acc[2][1] += a.z * bb.y; acc[2][2] += a.z * bb.z; acc[2][3] += a.z * bb.w;
            acc[3][0] += a.w * bb.x; acc[3][1] += a.w * bb.y; acc[3][2] += a.w * bb.z; acc[3][3] += a.w * bb.w;
        }
        __syncthreads();
    }
    if (tx < 12) {
#pragma unroll
        for (int i = 0; i < 4; i++) {
            int l = l0 + ty * 4 + i;
            if (l <= lb) {
                float4 v = make_float4(acc[i][0], acc[i][1], acc[i][2], acc[i][3]);
                *(float4*)(xd + (size_t)(b * L_ + l) * E48 + tx * 4) = v;
            }
        }
    }
}

// ---- scan phase A: per (b, chunk) local recurrence from h=0, dt fused in ----
__global__ __launch_bounds__(512) void k_scanA(const int* __restrict__ slen,
        const float* __restrict__ A_log, const float* __restrict__ w_dt,
        const float* __restrict__ b_dt, float* __restrict__ ws) {
    int b = blockIdx.y, g = blockIdx.x;
    int lb = slen[b] - 1;
    if (g * LC > lb) return;
    int d = threadIdx.x;
    const float* xs = ws + O_XS;
    const float* xdbl = ws + O_XDBL;
    float An[16], Wd[16];
#pragma unroll
    for (int q = 0; q < 4; q++) {
        float4 a = *(const float4*)(A_log + (size_t)d * 16 + q * 4);
        An[q * 4 + 0] = -__expf(a.x); An[q * 4 + 1] = -__expf(a.y);
        An[q * 4 + 2] = -__expf(a.z); An[q * 4 + 3] = -__expf(a.w);
        float4 w = *(const float4*)(w_dt + (size_t)d * 16 + q * 4);
        Wd[q * 4 + 0] = w.x; Wd[q * 4 + 1] = w.y; Wd[q * 4 + 2] = w.z; Wd[q * 4 + 3] = w.w;
    }
    float bd = b_dt[d];
    float h[16];
#pragma unroll
    for (int n = 0; n < 16; n++) h[n] = 0.f;
    float sdt = 0.f;
    int imax = min(LC - 1, lb - g * LC);
    for (int i = 0; i <= imax; i++) {
        size_t rbase = (size_t)(b * L_ + g * LC + i);
        const float4* rp = (const float4*)(xdbl + rbase * E48);
        float4 q0 = rp[0], q1 = rp[1], q2 = rp[2], q3 = rp[3];   // dt_raw[16]
        float4 B0 = rp[4], B1 = rp[5], B2 = rp[6], B3 = rp[7];   // B[16]
        float acc = bd;
        acc = fmaf(q0.x, Wd[0], acc);  acc = fmaf(q0.y, Wd[1], acc);
        acc = fmaf(q0.z, Wd[2], acc);  acc = fmaf(q0.w, Wd[3], acc);
        acc = fmaf(q1.x, Wd[4], acc);  acc = fmaf(q1.y, Wd[5], acc);
        acc = fmaf(q1.z, Wd[6], acc);  acc = fmaf(q1.w, Wd[7], acc);
        acc = fmaf(q2.x, Wd[8], acc);  acc = fmaf(q2.y, Wd[9], acc);
        acc = fmaf(q2.z, Wd[10], acc); acc = fmaf(q2.w, Wd[11], acc);
        acc = fmaf(q3.x, Wd[12], acc); acc = fmaf(q3.y, Wd[13], acc);
        acc = fmaf(q3.z, Wd[14], acc); acc = fmaf(q3.w, Wd[15], acc);
        float dtv = softplusf(acc);
        sdt += dtv;
        float xv = xs[rbase * DI + d];
        float w = dtv * xv;
        float Bv[16] = {B0.x, B0.y, B0.z, B0.w, B1.x, B1.y, B1.z, B1.w,
                        B2.x, B2.y, B2.z, B2.w, B3.x, B3.y, B3.z, B3.w};
#pragma unroll
        for (int n = 0; n < 16; n++) h[n] = fmaf(__expf(dtv * An[n]), h[n], w * Bv[n]);
    }
    float* Lg = ws + O_LG + ((size_t)(b * GCH + g) * DI + d) * 16;
#pragma unroll
    for (int q = 0; q < 4; q++)
        *(float4*)(Lg + q * 4) = make_float4(h[q * 4], h[q * 4 + 1], h[q * 4 + 2], h[q * 4 + 3]);
    ws[O_TSUM + (size_t)(b * GCH + g) * DI + d] = sdt;
}

// ---- scan phase B: combine chunks, produce y at lb, apply D-skip and silu(z) ----
__global__ void k_scanB(const int* __restrict__ slen, const float* __restrict__ A_log,
                        const float* __restrict__ Dp, float* __restrict__ ws) {
    int b = blockIdx.y;
    int d = blockIdx.x * 256 + threadIdx.x;
    int lb = slen[b] - 1, gb = lb >> 6;
    float An[16];
#pragma unroll
    for (int n = 0; n < 16; n++) An[n] = -__expf(A_log[(size_t)d * 16 + n]);
    float h[16];
#pragma unroll
    for (int n = 0; n < 16; n++) h[n] = 0.f;
    float R = 0.f;
    for (int g = gb; g >= 0; g--) {
        const float4* Lg = (const float4*)(ws + O_LG + ((size_t)(b * GCH + g) * DI + d) * 16);
        float4 v0 = Lg[0], v1 = Lg[1], v2 = Lg[2], v3 = Lg[3];
        float lv[16] = {v0.x, v0.y, v0.z, v0.w, v1.x, v1.y, v1.z, v1.w,
                        v2.x, v2.y, v2.z, v2.w, v3.x, v3.y, v3.z, v3.w};
        float T = ws[O_TSUM + (size_t)(b * GCH + g) * DI + d];
#pragma unroll
        for (int n = 0; n < 16; n++) h[n] = fmaf(__expf(An[n] * R), lv[n], h[n]);
        R += T;
    }
    const float* C = ws + O_XDBL + (size_t)(b * L_ + lb) * E48 + 32;
    float y = 0.f;
#pragma unroll
    for (int n = 0; n < 16; n++) y += h[n] * C[n];
    float xv = ws[O_XS + (size_t)(b * L_ + lb) * DI + d];
    y = (y + xv * Dp[d]) * ws[O_ZS + (size_t)b * DI + d];
    ws[O_YF + (size_t)b * DI + d] = y;
}

// ---- head: out_proj -> relu MLP -> scalar ----
__global__ __launch_bounds__(256) void k_head(const float* __restrict__ w_out,
        const float* __restrict__ w1, const float* __restrict__ b1,
        const float* __restrict__ w2, const float* __restrict__ b2,
        const float* __restrict__ ws, float* __restrict__ out) {
    int b = blockIdx.x, t = threadIdx.x;
    __shared__ float sy[DI];
    __shared__ float sol[DM];
    __shared__ float red[256];
    *(float2*)&sy[t * 2] = *(const float2*)(ws + O_YF + (size_t)b * DI + t * 2);
    __syncthreads();
    {
        float acc = 0.f;
        const float* wr = w_out + (size_t)t * DI;
        for (int k = 0; k < DI; k++) acc += sy[k] * wr[k];
        sol[t] = acc;
    }
    __syncthreads();
    float part = 0.f;
    for (int dd = 0; dd < 2; dd++) {
        int j = t + dd * 256;
        float acc = b1[j];
        const float* wr = w1 + (size_t)j * DM;
        for (int k = 0; k < DM; k++) acc += sol[k] * wr[k];
        part += fmaxf(acc, 0.f) * w2[j];
    }
    red[t] = part;
    __syncthreads();
    for (int s = 128; s > 0; s >>= 1) { if (t < s) red[t] += red[t + s]; __syncthreads(); }
    if (t == 0) out[b] = red[0] + b2[0];
}

extern "C" void kernel_launch(void* const* d_in, const int* in_sizes, int n_in,
                              void* d_out, int out_size, void* d_ws, size_t ws_size,
                              hipStream_t stream) {
    const int* rna = (const int*)d_in[0];
    const int* tid_ = (const int*)d_in[1];
    const int* slen = (const int*)d_in[2];
    const float* tis_emb = (const float*)d_in[3];
    const float* seq_emb = (const float*)d_in[4];
    const float* w_in = (const float*)d_in[5];
    const float* conv_w = (const float*)d_in[6];
    const float* conv_b = (const float*)d_in[7];
    const float* w_x = (const float*)d_in[8];
    const float* w_dt = (const float*)d_in[9];
    const float* b_dt = (const float*)d_in[10];
    const float* A_log = (const float*)d_in[11];
    const float* Dp = (const float*)d_in[12];
    const float* w_out = (const float*)d_in[13];
    const float* w1 = (const float*)d_in[14];
    const float* b1 = (const float*)d_in[15];
    const float* w2 = (const float*)d_in[16];
    const float* b2 = (const float*)d_in[17];
    float* ws = (float*)d_ws;
    float* out = (float*)d_out;

    hipLaunchKernelGGL(k_prep, dim3(192), dim3(256), 0, stream, w_in, w_x, ws);
    hipLaunchKernelGGL(k_zlast, dim3(16), dim3(256), 0, stream,
                       rna, tid_, slen, tis_emb, seq_emb, w_in, ws);
    hipLaunchKernelGGL(k_gemm1, dim3(8, 256), dim3(256), 0, stream,
                       rna, tid_, slen, tis_emb, seq_emb, ws);
    hipLaunchKernelGGL(k_conv, dim3(16, 16), dim3(256), 0, stream, slen, conv_w, conv_b, ws);
    hipLaunchKernelGGL(k_xdbl, dim3(256), dim3(256), 0, stream, slen, ws);
    hipLaunchKernelGGL(k_scanA, dim3(16, 16), dim3(512), 0, stream, slen, A_log, w_dt, b_dt, ws);
    hipLaunchKernelGGL(k_scanB, dim3(2, 16), dim3(256), 0, stream, slen, A_log, Dp, ws);
    hipLaunchKernelGGL(k_head, dim3(16), dim3(256), 0, stream, w_out, w1, b1, w2, b2, ws, out);
}